// Round 5
// baseline (243.251 us; speedup 1.0000x reference)
//
#include <hip/hip_runtime.h>

// Laplace transform forward: out[n,i,f] = e[i]*out[n-1,i,f] + decay[i]*inp[n,f]
// T=2048, F=256, N_S=108. float32 in / float32 out.
//
// Time-parallel: e[i] <= exp(-4/22.574) = 0.8376 => e^48 ~ 2e-4; contributions
// older than 48 steps are < ~6e-3 absolute (threshold 0.1625, measured 0.031).
// Each chunk of 64 outputs warms up 48 steps from zero state.
//
// R4 post-mortem: kernel portion ~94us vs 36us write roofline; 3.4 waves/SIMD
// can't hide the per-iter load->fma->store chain. This round: split the
// feature dim across 2 waves (float2/lane) -> 1728 blocks = 6.75 waves/SIMD,
// same total work, no extra warm-up redundancy.

#define T_LEN 2048
#define F_DIM 256
#define NS    108      // NTAU + 2*K = 100 + 8
#define KPAD  4
#define CHUNK 64
#define WARM  48

typedef float f32x2 __attribute__((ext_vector_type(2)));

__global__ __launch_bounds__(256) void laplace_kernel(
    const float* __restrict__ inp,   // (T, F) f32
    float* __restrict__ out)         // (T, NS, F) f32
{
    const int tid  = threadIdx.x;
    const int lane = tid & 63;
    const int w    = tid >> 6;                        // wave 0..3
    const int i    = blockIdx.y * 2 + (w >> 1);       // 2 taustars per block
    const int f0   = (w & 1) * 128 + lane * 2;        // 2 f-halves per taustar
    const int n0   = blockIdx.x * CHUNK;              // time chunk start

    // per-taustar constants (once per thread; ~2% tolerance, powf/expf fine)
    const float c     = powf(20.0f, 1.0f / 99.0f) - 1.0f;
    const float tau   = powf(1.0f + c, (float)(i - KPAD));
    const float s     = 4.0f / tau;
    const float e     = expf(-s);
    const float decay = (1.0f - e) / s;

    const float* ip = inp + f0;

    float t0 = 0.0f, t1 = 0.0f;

    // warm-up: recover state from the previous WARM inputs (exact for chunk 0)
    int nstart = n0 - WARM;
    if (nstart < 0) nstart = 0;
    #pragma unroll 4
    for (int n = nstart; n < n0; ++n) {
        f32x2 x = *(const f32x2*)(ip + (size_t)n * F_DIM);
        t0 = fmaf(e, t0, decay * x.x);
        t1 = fmaf(e, t1, decay * x.y);
    }

    // main: compute and store CHUNK outputs (nontemporal — never reread)
    float* op = out + (size_t)i * F_DIM + f0;
    #pragma unroll 4
    for (int n = n0; n < n0 + CHUNK; ++n) {
        f32x2 x = *(const f32x2*)(ip + (size_t)n * F_DIM);
        t0 = fmaf(e, t0, decay * x.x);
        t1 = fmaf(e, t1, decay * x.y);
        f32x2 r; r.x = t0; r.y = t1;
        __builtin_nontemporal_store(r, (f32x2*)(op + (size_t)n * (NS * F_DIM)));
    }
}

extern "C" void kernel_launch(void* const* d_in, const int* in_sizes, int n_in,
                              void* d_out, int out_size, void* d_ws, size_t ws_size,
                              hipStream_t stream) {
    const float* inp = (const float*)d_in[0];
    float* out = (float*)d_out;

    dim3 grid(T_LEN / CHUNK, NS / 2);   // 32 x 54 = 1728 blocks, 27 waves/CU
    laplace_kernel<<<grid, 256, 0, stream>>>(inp, out);
}